// Round 6
// baseline (697.213 us; speedup 1.0000x reference)
//
#include <hip/hip_runtime.h>
#include <stdint.h>

#define CB 32
#define CT 512
#define CK 256

typedef _Float16 half2_t __attribute__((ext_vector_type(2)));

__device__ inline float dot2f(half2_t a, half2_t b, float c) {
#if __has_builtin(__builtin_amdgcn_fdot2)
    return __builtin_amdgcn_fdot2(a, b, c, false);
#else
    asm("v_dot2_f32_f16 %0, %1, %2, %0" : "+v"(c) : "v"(a), "v"(b));
    return c;
#endif
}

__device__ inline half2_t bch2u(uint32_t u) { return __builtin_bit_cast(half2_t, u); }

__device__ inline uint32_t pk2(float a, float b) {
    return __builtin_bit_cast(uint32_t,
        __builtin_amdgcn_cvt_pkrtz(__expf(a), __expf(b)));
}

// Barrier that drains LDS ops but leaves global-load (vmcnt) prefetches in flight.
__device__ inline void lds_barrier() {
    asm volatile("s_waitcnt lgkmcnt(0)\n\ts_barrier" ::: "memory");
}

// E var n covers transition rows rowbase+8n .. rowbase+8n+7 for column `col`.
#define MKE(n) uint4 E##n; { const float* tp = trans + (size_t)(rowbase + (n) * 8) * CK + col; \
    E##n.x = pk2(tp[0], tp[CK]);                                           \
    E##n.y = pk2(tp[2 * CK], tp[3 * CK]);                                  \
    E##n.z = pk2(tp[4 * CK], tp[5 * CK]);                                  \
    E##n.w = pk2(tp[6 * CK], tp[7 * CK]); }

// p-pairs for E var n via in-wave readlane broadcast (SGPR), no LDS traffic.
// Lane l holds p-words 2l,2l+1 (pcx,pcy). Pair g = 64*half + 4n + d lives in
// lane rlbase + 2n + (d>>1), component d&1.
#define DOTRL(n, accA, accB) {                                               \
    const uint32_t q0 = __builtin_amdgcn_readlane(pcx, rlbase + 2 * (n));    \
    const uint32_t q1 = __builtin_amdgcn_readlane(pcy, rlbase + 2 * (n));    \
    const uint32_t q2 = __builtin_amdgcn_readlane(pcx, rlbase + 2 * (n) + 1);\
    const uint32_t q3 = __builtin_amdgcn_readlane(pcy, rlbase + 2 * (n) + 1);\
    accA = dot2f(bch2u(q0), bch2u(E##n.x), accA);                            \
    accB = dot2f(bch2u(q1), bch2u(E##n.y), accB);                            \
    accA = dot2f(bch2u(q2), bch2u(E##n.z), accA);                            \
    accB = dot2f(bch2u(q3), bch2u(E##n.w), accB); }

// 512 threads (8 waves) per chain. Thread t: col = t&255, half = t>>8, holds
// E[half*128 .. half*128+127, col] as 16 named uint4 (64 VGPRs, resident).
// Per step: [A] threads<256 publish p = exp(a - m_wave) as f16 (one b16 write);
//           [B] every wave pulls the whole p-vector with ONE per-lane ds_read_b64,
//               then 64 readlane + 64 dot2 per thread (VALU-only dot);
//           [C] threads<256 combine 4 partials with exp(m_w - M) scales.
__global__ __launch_bounds__(512, 2) void crf_chain_kernel(
    const float* __restrict__ emissions,    // [B,T,K]
    const int* __restrict__ tags,           // [B,T]
    const int* __restrict__ mask,           // [B,T] (bool -> int32)
    const float* __restrict__ trans,        // [K,K]
    float* __restrict__ ws)                 // ws[0..31]=log_den, ws[32..63]=log_num
{
    const int b = blockIdx.x;
    const int tid = threadIdx.x;
    const int col = tid & (CK - 1);
    const int half = tid >> 8;
    const int rowbase = half * 128;
    const int rlbase = half * 32;
    const int j = tid;                       // alpha owner when tid < CK
    const int wid = tid >> 6;
    const int lane = tid & 63;

    __shared__ __align__(16) _Float16 pbuf[CK];
    __shared__ __align__(16) float wmax[4];
    __shared__ float sbuf[4][CK];
    __shared__ float mask_lds[CT];
    __shared__ float red[8];

    const float* emB = emissions + (size_t)b * CT * CK;
    const int* tagB = tags + b * CT;
    const int* maskB = mask + b * CT;

    // ---------------- numerator (one t per thread: CT == 512) ----------------
    {
        const int t = tid;
        float mf = maskB[t] ? 1.f : 0.f;
        float num = emB[(size_t)t * CK + tagB[t]] * mf;
        if (t >= 1) num += trans[(size_t)tagB[t - 1] * CK + tagB[t]] * mf;
        #pragma unroll
        for (int off = 32; off > 0; off >>= 1) num += __shfl_down(num, off, 64);
        if (lane == 0) red[wid] = num;
        __syncthreads();
        if (tid == 0) {
            float s = 0.f;
            #pragma unroll
            for (int w = 0; w < 8; ++w) s += red[w];
            ws[CB + b] = s;
        }
        mask_lds[tid] = maskB[tid] ? 1.f : 0.f;
    }

    // ------------- E half-column: 16 named uint4 = 64 VGPRs -------------
    MKE(0)  MKE(1)  MKE(2)  MKE(3)  MKE(4)  MKE(5)  MKE(6)  MKE(7)
    MKE(8)  MKE(9)  MKE(10) MKE(11) MKE(12) MKE(13) MKE(14) MKE(15)
    __syncthreads();

    // ---------------- forward recursion ----------------
    float aj = 0.f, emit_next = 0.f;
    if (tid < CK) {
        aj = emB[j];                     // alpha at t=0
        emit_next = emB[CK + j];         // prefetch t=1
    }

    for (int t = 1; t < CT; ++t) {
        float emit_t = emit_next;

        // phase A: alpha owners publish p = exp(a - m_wave) <= 1 as f16
        if (tid < CK) {
            const int nxt = (t + 1 < CT) ? (t + 1) : (CT - 1);
            emit_next = emB[(size_t)nxt * CK + j];   // in flight across barriers
            float m = aj;
            #pragma unroll
            for (int off = 1; off < 64; off <<= 1) m = fmaxf(m, __shfl_xor(m, off, 64));
            if (lane == 0) wmax[wid] = m;
            pbuf[j] = (_Float16)__expf(aj - m);
        }
        lds_barrier();

        // phase B: one per-lane ds_read_b64 pulls the whole p-vector into the
        // wave (lane l -> p-words 2l,2l+1); dot via readlane+SGPR, zero DS.
        const uint2 pc = *reinterpret_cast<const uint2*>(&pbuf[4 * lane]);
        const uint32_t pcx = pc.x, pcy = pc.y;

        float a0 = 0.f, a1 = 0.f;
        DOTRL(0, a0, a1) DOTRL(1, a0, a1) DOTRL(2, a0, a1) DOTRL(3, a0, a1)
        DOTRL(4, a0, a1) DOTRL(5, a0, a1) DOTRL(6, a0, a1) DOTRL(7, a0, a1)
        float b0 = 0.f, b1 = 0.f;
        DOTRL(8, b0, b1)  DOTRL(9, b0, b1)  DOTRL(10, b0, b1) DOTRL(11, b0, b1)
        DOTRL(12, b0, b1) DOTRL(13, b0, b1) DOTRL(14, b0, b1) DOTRL(15, b0, b1)
        sbuf[half * 2 + 0][col] = a0 + a1;
        sbuf[half * 2 + 1][col] = b0 + b1;

        // scales (alpha owners): consume wmax here, before it is overwritten
        float f0 = 0.f, f1 = 0.f, f2 = 0.f, f3 = 0.f, M = 0.f;
        if (tid < CK) {
            const float4 wm = *reinterpret_cast<const float4*>(wmax);
            M = fmaxf(fmaxf(wm.x, wm.y), fmaxf(wm.z, wm.w));
            f0 = __expf(wm.x - M); f1 = __expf(wm.y - M);
            f2 = __expf(wm.z - M); f3 = __expf(wm.w - M);
        }
        lds_barrier();

        // phase C: combine partials, update alpha
        if (tid < CK) {
            float s = f0 * sbuf[0][j];
            s = fmaf(f1, sbuf[1][j], s);
            s = fmaf(f2, sbuf[2][j], s);
            s = fmaf(f3, sbuf[3][j], s);
            const float anew = M + __logf(s) + emit_t;
            aj = (mask_lds[t] != 0.f) ? anew : aj;
        }
        // sbuf reads here precede next iteration's first barrier; next sbuf
        // writes happen after it. pbuf/wmax hazards likewise barrier-separated.
    }

    // ---------------- final logsumexp over j (alpha owners only) ----------------
    if (tid < CK) {
        float mx = aj;
        #pragma unroll
        for (int off = 32; off > 0; off >>= 1) mx = fmaxf(mx, __shfl_down(mx, off, 64));
        mx = __shfl(mx, 0, 64);
        if (lane == 0) red[wid] = mx;
    }
    __syncthreads();
    if (tid < CK) {
        const float gmx = fmaxf(fmaxf(red[0], red[1]), fmaxf(red[2], red[3]));
        float ex = __expf(aj - gmx);
        #pragma unroll
        for (int off = 32; off > 0; off >>= 1) ex += __shfl_down(ex, off, 64);
        if (lane == 0) red[4 + wid] = ex;
    }
    __syncthreads();
    if (tid == 0) {
        const float gmx = fmaxf(fmaxf(red[0], red[1]), fmaxf(red[2], red[3]));
        ws[b] = gmx + __logf(red[4] + red[5] + red[6] + red[7]);
    }
}

__global__ void crf_finalize_kernel(const float* __restrict__ ws,
                                    float* __restrict__ out) {
    float v = 0.f;
    if ((int)threadIdx.x < CB) v = ws[threadIdx.x] - ws[CB + threadIdx.x];
    #pragma unroll
    for (int off = 32; off > 0; off >>= 1) v += __shfl_down(v, off, 64);
    if (threadIdx.x == 0) out[0] = v * (1.f / CB);
}

extern "C" void kernel_launch(void* const* d_in, const int* in_sizes, int n_in,
                              void* d_out, int out_size, void* d_ws, size_t ws_size,
                              hipStream_t stream) {
    const float* emissions = (const float*)d_in[0];
    const int* tags = (const int*)d_in[1];
    const int* mask = (const int*)d_in[2];
    const float* trans = (const float*)d_in[3];
    float* out = (float*)d_out;
    float* ws = (float*)d_ws;

    crf_chain_kernel<<<CB, 512, 0, stream>>>(emissions, tags, mask, trans, ws);
    crf_finalize_kernel<<<1, 64, 0, stream>>>(ws, out);
}

// Round 8
// 421.487 us; speedup vs baseline: 1.6542x; 1.6542x over previous
//
#include <hip/hip_runtime.h>
#include <stdint.h>

#define CB 32
#define CT 512
#define CK 256

typedef _Float16 half2_t __attribute__((ext_vector_type(2)));

__device__ inline float dot2f(half2_t a, half2_t b, float c) {
#if __has_builtin(__builtin_amdgcn_fdot2)
    return __builtin_amdgcn_fdot2(a, b, c, false);
#else
    asm("v_dot2_f32_f16 %0, %1, %2, %0" : "+v"(c) : "v"(a), "v"(b));
    return c;
#endif
}

__device__ inline half2_t bch2(float f) { return __builtin_bit_cast(half2_t, f); }
__device__ inline half2_t bch2u(uint32_t u) { return __builtin_bit_cast(half2_t, u); }

__device__ inline uint32_t pk2(float a, float b) {
    return __builtin_bit_cast(uint32_t,
        __builtin_amdgcn_cvt_pkrtz(__expf(a), __expf(b)));
}

// Barrier that drains LDS ops but leaves global-load (vmcnt) prefetches in flight.
__device__ inline void lds_barrier() {
    asm volatile("s_waitcnt lgkmcnt(0)\n\ts_barrier" ::: "memory");
}

// E var (i,c): rows rowbase+8i .. rowbase+8i+7, column col0+c, packed as
// 4 half2 row-pairs (matches p float4 chunk layout).
#define MKE(i, c) uint4 E_##i##_##c; {                                      \
    const float* tp = trans + (size_t)(rowbase + (i) * 8) * CK + (col0 + (c)); \
    E_##i##_##c.x = pk2(tp[0],      tp[CK]);                                \
    E_##i##_##c.y = pk2(tp[2 * CK], tp[3 * CK]);                            \
    E_##i##_##c.z = pk2(tp[4 * CK], tp[5 * CK]);                            \
    E_##i##_##c.w = pk2(tp[6 * CK], tp[7 * CK]); }

// One p half2 (qm) dotted against the matching member m of all 4 column vars.
#define DOT4(i, qm, m) {                                                    \
    acc0 = dot2f(qm, bch2u(E_##i##_0.m), acc0);                             \
    acc1 = dot2f(qm, bch2u(E_##i##_1.m), acc1);                             \
    acc2 = dot2f(qm, bch2u(E_##i##_2.m), acc2);                             \
    acc3 = dot2f(qm, bch2u(E_##i##_3.m), acc3); }

// One broadcast 8-value p-chunk (float4 = 4 half2) reused across 4 columns.
#define DOTCHUNK(i) {                                                       \
    const float4 q = *reinterpret_cast<const float4*>(&pbuf[rowbase + (i) * 8]); \
    DOT4(i, bch2(q.x), x)                                                   \
    DOT4(i, bch2(q.y), y)                                                   \
    DOT4(i, bch2(q.z), z)                                                   \
    DOT4(i, bch2(q.w), w) }

// 512 threads (8 waves) per chain. Thread t: rowchunk q = t>>6 (wave-uniform),
// cols col0 = (t&63)*4 .. +3; holds E[32q..32q+31, col0..col0+3] as 16 uint4
// (64 VGPRs). Per step:
//   [A] threads<256 publish p = exp(a - m_wave) as f16;
//   [B] 4 broadcast b128 p-reads (wave-uniform addr), 64 dot2, ONE float4
//       partial write to sbuf[q][col0];
//   [C] threads<256 combine 8 partials with wave scales f[q>>1].
__global__ __launch_bounds__(512, 2) void crf_chain_kernel(
    const float* __restrict__ emissions,    // [B,T,K]
    const int* __restrict__ tags,           // [B,T]
    const int* __restrict__ mask,           // [B,T] (bool -> int32)
    const float* __restrict__ trans,        // [K,K]
    float* __restrict__ ws)                 // ws[0..31]=log_den, ws[32..63]=log_num
{
    const int b = blockIdx.x;
    const int tid = threadIdx.x;
    const int q = tid >> 6;                  // rowchunk, wave-uniform
    const int rowbase = q * 32;
    const int col0 = (tid & 63) * 4;
    const int j = tid;                       // alpha owner when tid < CK
    const int wid = tid >> 6;
    const int lane = tid & 63;

    __shared__ __align__(16) _Float16 pbuf[CK];
    __shared__ __align__(16) float wmax[4];
    __shared__ __align__(16) float sbuf[8][CK];
    __shared__ float mask_lds[CT];
    __shared__ float red[8];

    const float* emB = emissions + (size_t)b * CT * CK;
    const int* tagB = tags + b * CT;
    const int* maskB = mask + b * CT;

    // ---------------- numerator (one t per thread: CT == 512) ----------------
    {
        const int t = tid;
        float mf = maskB[t] ? 1.f : 0.f;
        float num = emB[(size_t)t * CK + tagB[t]] * mf;
        if (t >= 1) num += trans[(size_t)tagB[t - 1] * CK + tagB[t]] * mf;
        #pragma unroll
        for (int off = 32; off > 0; off >>= 1) num += __shfl_down(num, off, 64);
        if (lane == 0) red[wid] = num;
        __syncthreads();
        if (tid == 0) {
            float s = 0.f;
            #pragma unroll
            for (int w = 0; w < 8; ++w) s += red[w];
            ws[CB + b] = s;
        }
        mask_lds[tid] = maskB[tid] ? 1.f : 0.f;
    }

    // ------------- E block: 16 named uint4 = 64 VGPRs -------------
    MKE(0,0) MKE(0,1) MKE(0,2) MKE(0,3)
    MKE(1,0) MKE(1,1) MKE(1,2) MKE(1,3)
    MKE(2,0) MKE(2,1) MKE(2,2) MKE(2,3)
    MKE(3,0) MKE(3,1) MKE(3,2) MKE(3,3)
    __syncthreads();

    // ---------------- forward recursion ----------------
    float aj = 0.f, emit_next = 0.f;
    if (tid < CK) {
        aj = emB[j];                     // alpha at t=0
        emit_next = emB[CK + j];         // prefetch t=1
    }

    for (int t = 1; t < CT; ++t) {
        float emit_t = emit_next;

        // phase A: alpha owners publish p = exp(a - m_wave) <= 1 as f16
        if (tid < CK) {
            const int nxt = (t + 1 < CT) ? (t + 1) : (CT - 1);
            emit_next = emB[(size_t)nxt * CK + j];   // in flight across barriers
            float m = aj;
            #pragma unroll
            for (int off = 1; off < 64; off <<= 1) m = fmaxf(m, __shfl_xor(m, off, 64));
            if (lane == 0) wmax[wid] = m;
            pbuf[j] = (_Float16)__expf(aj - m);
        }
        lds_barrier();

        // phase B: 4 broadcast p-chunks, 64 dot2, one float4 partial write
        float acc0 = 0.f, acc1 = 0.f, acc2 = 0.f, acc3 = 0.f;
        DOTCHUNK(0) DOTCHUNK(1) DOTCHUNK(2) DOTCHUNK(3)
        *reinterpret_cast<float4*>(&sbuf[q][col0]) =
            make_float4(acc0, acc1, acc2, acc3);

        // scales (alpha owners): consume wmax here, before it is overwritten
        float f0 = 0.f, f1 = 0.f, f2 = 0.f, f3 = 0.f, M = 0.f;
        if (tid < CK) {
            const float4 wm = *reinterpret_cast<const float4*>(wmax);
            M = fmaxf(fmaxf(wm.x, wm.y), fmaxf(wm.z, wm.w));
            f0 = __expf(wm.x - M); f1 = __expf(wm.y - M);
            f2 = __expf(wm.z - M); f3 = __expf(wm.w - M);
        }
        lds_barrier();

        // phase C: combine 8 rowchunk partials (chunks 2w,2w+1 share scale f_w)
        if (tid < CK) {
            float s = f0 * (sbuf[0][j] + sbuf[1][j]);
            s = fmaf(f1, sbuf[2][j] + sbuf[3][j], s);
            s = fmaf(f2, sbuf[4][j] + sbuf[5][j], s);
            s = fmaf(f3, sbuf[6][j] + sbuf[7][j], s);
            const float anew = M + __logf(s) + emit_t;
            aj = (mask_lds[t] != 0.f) ? anew : aj;
        }
        // sbuf reads here precede next iteration's first barrier; next sbuf
        // writes happen after it. pbuf/wmax hazards likewise barrier-separated.
    }

    // ---------------- final logsumexp over j (alpha owners only) ----------------
    if (tid < CK) {
        float mx = aj;
        #pragma unroll
        for (int off = 32; off > 0; off >>= 1) mx = fmaxf(mx, __shfl_down(mx, off, 64));
        mx = __shfl(mx, 0, 64);
        if (lane == 0) red[wid] = mx;
    }
    __syncthreads();
    if (tid < CK) {
        const float gmx = fmaxf(fmaxf(red[0], red[1]), fmaxf(red[2], red[3]));
        float ex = __expf(aj - gmx);
        #pragma unroll
        for (int off = 32; off > 0; off >>= 1) ex += __shfl_down(ex, off, 64);
        if (lane == 0) red[4 + wid] = ex;
    }
    __syncthreads();
    if (tid == 0) {
        const float gmx = fmaxf(fmaxf(red[0], red[1]), fmaxf(red[2], red[3]));
        ws[b] = gmx + __logf(red[4] + red[5] + red[6] + red[7]);
    }
}

__global__ void crf_finalize_kernel(const float* __restrict__ ws,
                                    float* __restrict__ out) {
    float v = 0.f;
    if ((int)threadIdx.x < CB) v = ws[threadIdx.x] - ws[CB + threadIdx.x];
    #pragma unroll
    for (int off = 32; off > 0; off >>= 1) v += __shfl_down(v, off, 64);
    if (threadIdx.x == 0) out[0] = v * (1.f / CB);
}

extern "C" void kernel_launch(void* const* d_in, const int* in_sizes, int n_in,
                              void* d_out, int out_size, void* d_ws, size_t ws_size,
                              hipStream_t stream) {
    const float* emissions = (const float*)d_in[0];
    const int* tags = (const int*)d_in[1];
    const int* mask = (const int*)d_in[2];
    const float* trans = (const float*)d_in[3];
    float* out = (float*)d_out;
    float* ws = (float*)d_ws;

    crf_chain_kernel<<<CB, 512, 0, stream>>>(emissions, tags, mask, trans, ws);
    crf_finalize_kernel<<<1, 64, 0, stream>>>(ws, out);
}